// Round 5
// baseline (269.291 us; speedup 1.0000x reference)
//
#include <hip/hip_runtime.h>
#include <stdint.h>
#include <math.h>

// RG-LRU: B=4, L=4096, D=1024.
//   r = sigmoid(x @ Wa^T + ba); i = sigmoid(x @ Wx^T + bx)
//   e = 8*r*log2(sigmoid(lmbd));  a = exp2(e);  b = sqrt(1-a^2)*i*x
//   h_t = a_t*h_{t-1} + b_t
//
// R5: (1) g-half epilogue reads bf16 x from swizzled Xs (xf fp32 read dropped,
// FETCH -64MB). (2) scan phase1+phase3 fused via decoupled lookback
// (device-scope atomics; 512 blocks co-resident -> no deadlock; slots
// zeroed by pack_all so ws 0xAA poison can't fake a ready tag).

#define D_DIM 1024
#define L_DIM 4096
#define B_DIM 4
#define M_DIM (B_DIM * L_DIM)   // 16384
#define N_DIM (2 * D_DIM)       // 2048
#define K_DIM D_DIM             // 1024
#define NC 32
#define CL (L_DIM / NC)         // 128
#define L2E 1.4426950408889634f

typedef __attribute__((ext_vector_type(8))) short short8;
typedef __attribute__((ext_vector_type(4))) short short4v;
typedef __attribute__((ext_vector_type(4))) float float4v;

__device__ __forceinline__ unsigned short f2bf(float f) {
  unsigned u = __float_as_uint(f);
  u += 0x7fffu + ((u >> 16) & 1u);
  return (unsigned short)(u >> 16);
}
__device__ __forceinline__ float bf2f(unsigned short h) {
  return __uint_as_float((unsigned)h << 16);
}
__device__ __forceinline__ short f2h(float f) {
  _Float16 h = (_Float16)f;
  return __builtin_bit_cast(short, h);
}

#define NX16 (M_DIM * K_DIM / 8)        // 2097152 x-groups
#define NW16 (N_DIM * K_DIM / 8)        // 262144 w-groups
#define NSLOTS (B_DIM * NC * D_DIM)     // 131072 lookback slots

// Pack fp32 [rows][1024] -> swizzled bf16, 16B group index:
//   off16 = ((R*32 + k0)*4 + kc)*16 + r,  row = R*16+r, k = (k0*4+kc)*8.
// Also zero-inits the lookback slot array (tail threads).
__global__ void pack_all(const float* __restrict__ x, const float* __restrict__ Wa,
                         const float* __restrict__ Wx, short* __restrict__ Xs,
                         short* __restrict__ Ws, unsigned long long* __restrict__ slots) {
  int t = blockIdx.x * 256 + threadIdx.x;
  const float* src;
  short8* dst;
  int u;
  if (t < NX16) {
    u = t; src = x; dst = (short8*)Xs;
  } else if (t < NX16 + NW16) {
    u = t - NX16;
    dst = (short8*)Ws;
    int row = ((u >> 11) << 4) | (u & 15);
    src = (row < D_DIM) ? Wa : (Wx - (size_t)D_DIM * K_DIM);
  } else {
    int s = t - NX16 - NW16;
    if (s < NSLOTS) slots[s] = 0ULL;
    return;
  }
  int r  = u & 15;
  int kc = (u >> 4) & 3;
  int k0 = (u >> 6) & 31;
  int R  = u >> 11;
  int m = R * 16 + r;
  int k = (k0 * 4 + kc) * 8;
  const float4v* s4 = (const float4v*)(src + (size_t)m * 1024 + k);
  float4v v0 = s4[0], v1 = s4[1];
  short8 o;
  o[0] = (short)f2bf(v0.x); o[1] = (short)f2bf(v0.y);
  o[2] = (short)f2bf(v0.z); o[3] = (short)f2bf(v0.w);
  o[4] = (short)f2bf(v1.x); o[5] = (short)f2bf(v1.y);
  o[6] = (short)f2bf(v1.z); o[7] = (short)f2bf(v1.w);
  dst[u] = o;
}

// 128x128 tile, BK=32, 4 waves, 4x4 mfma_f32_16x16x32_bf16 per wave.
// Epilogue: per-wave 64x64 LDS transpose -> lane-contiguous stores of
// e (fp16, log2-domain) / g (bf16, x sourced from swizzled Xs).
__global__ __launch_bounds__(256, 4) void gemm_gates(
    const short* __restrict__ Xs,
    const short* __restrict__ Ws,
    const float* __restrict__ ba,
    const float* __restrict__ bx,
    const float* __restrict__ lmbd,
    short* __restrict__ e_out,          // [16384,1024] fp16: 8*r*log2(sig(lmbd))
    unsigned short* __restrict__ g_out) // [16384,1024] bf16: i*x
{
  __shared__ __align__(16) char smem[17664];

  const int tile_n = blockIdx.x * 128;   // n fastest -> X panel shared by 16 blocks
  const int tile_m = blockIdx.y * 128;
  const int tid  = threadIdx.x;
  const int wave = tid >> 6;
  const int lane = tid & 63;
  const int row16 = lane & 15;
  const int quad  = lane >> 4;
  const int wave_m = (wave & 1) * 64;
  const int wave_n = (wave >> 1) * 64;

  short* As = (short*)smem;
  short* Bs = (short*)(smem + 8192);
  char* AsB = smem;
  char* BsB = smem + 8192;

  float4v acc[4][4] = {};

  for (int kk = 0; kk < 32; ++kk) {
#pragma unroll
    for (int p = 0; p < 2; ++p) {
      const int G = p * 4 + wave;
      const size_t RgA = (size_t)((tile_m >> 4) + G);
      const size_t RgB = (size_t)((tile_n >> 4) + G);
      __builtin_amdgcn_global_load_lds(
          (const __attribute__((address_space(1))) void*)(Xs + ((RgA * 32 + kk) * 64 + lane) * 8),
          (__attribute__((address_space(3))) void*)(AsB + G * 1024),
          16, 0, 0);
      __builtin_amdgcn_global_load_lds(
          (const __attribute__((address_space(1))) void*)(Ws + ((RgB * 32 + kk) * 64 + lane) * 8),
          (__attribute__((address_space(3))) void*)(BsB + G * 1024),
          16, 0, 0);
    }
    __syncthreads();

    short8 af[4], bfr[4];
#pragma unroll
    for (int i = 0; i < 4; ++i)
      af[i] = *(const short8*)&As[((wave & 1) * 4 + i) * 512 + lane * 8];
#pragma unroll
    for (int i = 0; i < 4; ++i)
      bfr[i] = *(const short8*)&Bs[((wave >> 1) * 4 + i) * 512 + lane * 8];

#pragma unroll
    for (int mi = 0; mi < 4; ++mi)
#pragma unroll
      for (int ni = 0; ni < 4; ++ni)
        acc[mi][ni] = __builtin_amdgcn_mfma_f32_16x16x32_bf16(af[mi], bfr[ni], acc[mi][ni], 0, 0, 0);
    __syncthreads();
  }

  // ---- Epilogue: per-wave 64x64 transpose through LDS (stride 68 floats) ----
  float* Ts = (float*)smem + (size_t)wave * (16 * 68);
  const int colg = (lane & 15) * 4;
  const int rrow = lane >> 4;
  const bool is_a = (tile_n < D_DIM);
  const int ch0 = (is_a ? tile_n : tile_n - D_DIM) + wave_n + colg;

  float4v bias4, la84;
  if (is_a) {
    bias4 = *(const float4v*)(ba + ch0);
    float4v lm4 = *(const float4v*)(lmbd + ch0);
#pragma unroll
    for (int k = 0; k < 4; ++k)
      la84[k] = -8.0f * __builtin_amdgcn_logf(1.0f + __builtin_amdgcn_exp2f(-lm4[k] * L2E));
  } else {
    bias4 = *(const float4v*)(bx + ch0);
  }
  // swizzled-Xs constant part of the x re-read address for this thread:
  //   short_off(m,ch) = (((m>>4)*32 + (ch>>5))*4 + ((ch>>3)&3))*16 + (m&15))*8 + (ch&7)
  const size_t xs_ch = ((size_t)(ch0 >> 5) * 4 + ((ch0 >> 3) & 3)) * 16 * 8 + (ch0 & 7);

#pragma unroll
  for (int mi = 0; mi < 4; ++mi) {
#pragma unroll
    for (int ni = 0; ni < 4; ++ni)
#pragma unroll
      for (int r = 0; r < 4; ++r)
        Ts[(quad * 4 + r) * 68 + ni * 16 + row16] = acc[mi][ni][r];
#pragma unroll
    for (int j = 0; j < 4; ++j) {
      int lr = j * 4 + rrow;
      float4v z = *(const float4v*)&Ts[lr * 68 + colg];
      size_t gm = (size_t)(tile_m + wave_m + mi * 16 + lr);
      short4v o;
      if (is_a) {
#pragma unroll
        for (int k = 0; k < 4; ++k) {
          float s = __builtin_amdgcn_rcpf(1.0f + __builtin_amdgcn_exp2f(-(z[k] + bias4[k]) * L2E));
          o[k] = f2h(s * la84[k]);
        }
        *(short4v*)(e_out + gm * D_DIM + ch0) = o;
      } else {
        short4v xq = *(const short4v*)(Xs + ((gm >> 4) * 32 * 64 + (gm & 15)) * 8 + xs_ch);
#pragma unroll
        for (int k = 0; k < 4; ++k) {
          float s = __builtin_amdgcn_rcpf(1.0f + __builtin_amdgcn_exp2f(-(z[k] + bias4[k]) * L2E));
          o[k] = (short)f2bf(s * bf2f((unsigned short)xq[k]));
        }
        *(short4v*)((short*)g_out + gm * D_DIM + ch0) = o;
      }
    }
  }
}

// Fused chunked scan with decoupled lookback.
// grid (4, NC, B): block = (dgroup, chunk c, batch b); 512 blocks co-resident.
__global__ __launch_bounds__(256) void scan_fused(
    const short* __restrict__ e, const unsigned short* __restrict__ g,
    unsigned long long* __restrict__ slots, float* __restrict__ y) {
  int d = blockIdx.x * 256 + threadIdx.x;
  int c = blockIdx.y;
  int b = blockIdx.z;
  const size_t base = ((size_t)(b * L_DIM + c * CL)) * D_DIM + d;

  // Phase A: local chunk composition (P = prod a, Q = local scan from 0).
  float Pv = 1.0f, Qv = 0.0f;
#pragma unroll 4
  for (int t = 0; t < CL; ++t) {
    float ev = (float)__builtin_bit_cast(_Float16, e[base + (size_t)t * D_DIM]);
    float at = __builtin_amdgcn_exp2f(ev);
    float gv = bf2f(g[base + (size_t)t * D_DIM]);
    float bt = sqrtf(fmaxf(1.0f - at * at, 0.0f)) * gv;
    Qv = fmaf(at, Qv, bt);
    Pv *= at;
  }

  // Lookback: wait for predecessor chunk's inclusive H (device-scope atomics;
  // slots zeroed by pack_all, tag=1 in hi word marks ready).
  float Hin = 0.0f;
  if (c > 0) {
    unsigned long long* sp = slots + ((size_t)(b * NC + c - 1) * D_DIM + d);
    unsigned long long v = atomicAdd(sp, 0ULL);
    while ((unsigned)(v >> 32) != 1u) {
      __builtin_amdgcn_s_sleep(8);
      v = atomicAdd(sp, 0ULL);
    }
    Hin = __uint_as_float((unsigned)v);
  }
  if (c < NC - 1) {
    float Hout = fmaf(Pv, Hin, Qv);
    atomicExch(slots + ((size_t)(b * NC + c) * D_DIM + d),
               (1ULL << 32) | (unsigned long long)__float_as_uint(Hout));
  }

  // Phase B: replay chunk from Hin (re-reads are L1/L2/L3-hot), write y.
  float h = Hin;
#pragma unroll 4
  for (int t = 0; t < CL; ++t) {
    float ev = (float)__builtin_bit_cast(_Float16, e[base + (size_t)t * D_DIM]);
    float at = __builtin_amdgcn_exp2f(ev);
    float gv = bf2f(g[base + (size_t)t * D_DIM]);
    float bt = sqrtf(fmaxf(1.0f - at * at, 0.0f)) * gv;
    h = fmaf(at, h, bt);
    y[base + (size_t)t * D_DIM] = h;
  }
}

extern "C" void kernel_launch(void* const* d_in, const int* in_sizes, int n_in,
                              void* d_out, int out_size, void* d_ws, size_t ws_size,
                              hipStream_t stream) {
  const float* x    = (const float*)d_in[0];
  const float* Wa   = (const float*)d_in[1];
  const float* Wx   = (const float*)d_in[2];
  const float* ba   = (const float*)d_in[3];
  const float* bx   = (const float*)d_in[4];
  const float* lmbd = (const float*)d_in[5];
  float* y = (float*)d_out;

  char* ws = (char*)d_ws;
  short* Xs                  = (short*)ws;                       // 32 MiB swizzled bf16 x
  short* Wsz                 = (short*)(ws + 33554432);          //  4 MiB swizzled bf16 [Wa;Wx]
  short* e_buf               = (short*)(ws + 37748736);          // 32 MiB fp16 e
  unsigned short* g_buf      = (unsigned short*)(ws + 71303168); // 32 MiB bf16 g
  unsigned long long* slots  = (unsigned long long*)(ws + 104857600); // 1 MiB lookback

  pack_all<<<(NX16 + NW16 + NSLOTS) / 256, 256, 0, stream>>>(x, Wa, Wx, Xs, Wsz, slots);

  dim3 gg(N_DIM / 128, M_DIM / 128);   // (16, 128), n fastest
  gemm_gates<<<gg, 256, 0, stream>>>(Xs, Wsz, ba, bx, lmbd, e_buf, g_buf);

  dim3 sg(D_DIM / 256, NC, B_DIM);     // (4, 32, 4)
  scan_fused<<<sg, 256, 0, stream>>>(e_buf, g_buf, slots, y);
}

// Round 6
// 251.473 us; speedup vs baseline: 1.0709x; 1.0709x over previous
//
#include <hip/hip_runtime.h>
#include <stdint.h>
#include <math.h>

// RG-LRU: B=4, L=4096, D=1024.
//   r = sigmoid(x @ Wa^T + ba); i = sigmoid(x @ Wx^T + bx)
//   e = 8*r*log2(sigmoid(lmbd));  a = exp2(e);  b = sqrt(1-a^2)*i*x
//   h_t = a_t*h_{t-1} + b_t
//
// R6: revert R5's serialized lookback -> R4's two-phase scan (phase3 does its
// own chunk prefix); NC=64 for 4 blocks/CU ramp; pack without slot tail.
// GEMM core unchanged from R5 (808 TF, m97-structure plateau).

#define D_DIM 1024
#define L_DIM 4096
#define B_DIM 4
#define M_DIM (B_DIM * L_DIM)   // 16384
#define N_DIM (2 * D_DIM)       // 2048
#define K_DIM D_DIM             // 1024
#define NC 64
#define CL (L_DIM / NC)         // 64
#define L2E 1.4426950408889634f

typedef __attribute__((ext_vector_type(8))) short short8;
typedef __attribute__((ext_vector_type(4))) short short4v;
typedef __attribute__((ext_vector_type(4))) float float4v;

__device__ __forceinline__ unsigned short f2bf(float f) {
  unsigned u = __float_as_uint(f);
  u += 0x7fffu + ((u >> 16) & 1u);
  return (unsigned short)(u >> 16);
}
__device__ __forceinline__ float bf2f(unsigned short h) {
  return __uint_as_float((unsigned)h << 16);
}
__device__ __forceinline__ short f2h(float f) {
  _Float16 h = (_Float16)f;
  return __builtin_bit_cast(short, h);
}

#define NX16 (M_DIM * K_DIM / 8)        // 2097152 x-groups
#define NW16 (N_DIM * K_DIM / 8)        // 262144 w-groups

// Pack fp32 [rows][1024] -> swizzled bf16, 16B group index:
//   off16 = ((R*32 + k0)*4 + kc)*16 + r,  row = R*16+r, k = (k0*4+kc)*8.
__global__ void pack_all(const float* __restrict__ x, const float* __restrict__ Wa,
                         const float* __restrict__ Wx, short* __restrict__ Xs,
                         short* __restrict__ Ws) {
  int t = blockIdx.x * 256 + threadIdx.x;
  const float* src;
  short8* dst;
  int u;
  if (t < NX16) {
    u = t; src = x; dst = (short8*)Xs;
  } else {
    u = t - NX16;
    if (u >= NW16) return;
    dst = (short8*)Ws;
    int row = ((u >> 11) << 4) | (u & 15);
    src = (row < D_DIM) ? Wa : (Wx - (size_t)D_DIM * K_DIM);
  }
  int r  = u & 15;
  int kc = (u >> 4) & 3;
  int k0 = (u >> 6) & 31;
  int R  = u >> 11;
  int m = R * 16 + r;
  int k = (k0 * 4 + kc) * 8;
  const float4v* s4 = (const float4v*)(src + (size_t)m * 1024 + k);
  float4v v0 = s4[0], v1 = s4[1];
  short8 o;
  o[0] = (short)f2bf(v0.x); o[1] = (short)f2bf(v0.y);
  o[2] = (short)f2bf(v0.z); o[3] = (short)f2bf(v0.w);
  o[4] = (short)f2bf(v1.x); o[5] = (short)f2bf(v1.y);
  o[6] = (short)f2bf(v1.z); o[7] = (short)f2bf(v1.w);
  dst[u] = o;
}

// 128x128 tile, BK=32, 4 waves, 4x4 mfma_f32_16x16x32_bf16 per wave.
// Staging conflict-free + coalesced (swizzled source); epilogue 64x64 LDS
// transpose -> lane-contiguous stores of e (fp16 log2-domain) / g (bf16).
__global__ __launch_bounds__(256, 4) void gemm_gates(
    const short* __restrict__ Xs,
    const short* __restrict__ Ws,
    const float* __restrict__ ba,
    const float* __restrict__ bx,
    const float* __restrict__ lmbd,
    short* __restrict__ e_out,          // [16384,1024] fp16: 8*r*log2(sig(lmbd))
    unsigned short* __restrict__ g_out) // [16384,1024] bf16: i*x
{
  __shared__ __align__(16) char smem[17664];

  const int tile_n = blockIdx.x * 128;   // n fastest -> X panel shared by 16 blocks
  const int tile_m = blockIdx.y * 128;
  const int tid  = threadIdx.x;
  const int wave = tid >> 6;
  const int lane = tid & 63;
  const int row16 = lane & 15;
  const int quad  = lane >> 4;
  const int wave_m = (wave & 1) * 64;
  const int wave_n = (wave >> 1) * 64;

  short* As = (short*)smem;
  short* Bs = (short*)(smem + 8192);
  char* AsB = smem;
  char* BsB = smem + 8192;

  float4v acc[4][4] = {};

  for (int kk = 0; kk < 32; ++kk) {
#pragma unroll
    for (int p = 0; p < 2; ++p) {
      const int G = p * 4 + wave;
      const size_t RgA = (size_t)((tile_m >> 4) + G);
      const size_t RgB = (size_t)((tile_n >> 4) + G);
      __builtin_amdgcn_global_load_lds(
          (const __attribute__((address_space(1))) void*)(Xs + ((RgA * 32 + kk) * 64 + lane) * 8),
          (__attribute__((address_space(3))) void*)(AsB + G * 1024),
          16, 0, 0);
      __builtin_amdgcn_global_load_lds(
          (const __attribute__((address_space(1))) void*)(Ws + ((RgB * 32 + kk) * 64 + lane) * 8),
          (__attribute__((address_space(3))) void*)(BsB + G * 1024),
          16, 0, 0);
    }
    __syncthreads();

    short8 af[4], bfr[4];
#pragma unroll
    for (int i = 0; i < 4; ++i)
      af[i] = *(const short8*)&As[((wave & 1) * 4 + i) * 512 + lane * 8];
#pragma unroll
    for (int i = 0; i < 4; ++i)
      bfr[i] = *(const short8*)&Bs[((wave >> 1) * 4 + i) * 512 + lane * 8];

#pragma unroll
    for (int mi = 0; mi < 4; ++mi)
#pragma unroll
      for (int ni = 0; ni < 4; ++ni)
        acc[mi][ni] = __builtin_amdgcn_mfma_f32_16x16x32_bf16(af[mi], bfr[ni], acc[mi][ni], 0, 0, 0);
    __syncthreads();
  }

  // ---- Epilogue: per-wave 64x64 transpose through LDS (stride 68 floats) ----
  float* Ts = (float*)smem + (size_t)wave * (16 * 68);
  const int colg = (lane & 15) * 4;
  const int rrow = lane >> 4;
  const bool is_a = (tile_n < D_DIM);
  const int ch0 = (is_a ? tile_n : tile_n - D_DIM) + wave_n + colg;

  float4v bias4, la84;
  if (is_a) {
    bias4 = *(const float4v*)(ba + ch0);
    float4v lm4 = *(const float4v*)(lmbd + ch0);
#pragma unroll
    for (int k = 0; k < 4; ++k)
      la84[k] = -8.0f * __builtin_amdgcn_logf(1.0f + __builtin_amdgcn_exp2f(-lm4[k] * L2E));
  } else {
    bias4 = *(const float4v*)(bx + ch0);
  }
  // swizzled-Xs constant part of the x re-read address for this thread
  const size_t xs_ch = ((size_t)(ch0 >> 5) * 4 + ((ch0 >> 3) & 3)) * 16 * 8 + (ch0 & 7);

#pragma unroll
  for (int mi = 0; mi < 4; ++mi) {
#pragma unroll
    for (int ni = 0; ni < 4; ++ni)
#pragma unroll
      for (int r = 0; r < 4; ++r)
        Ts[(quad * 4 + r) * 68 + ni * 16 + row16] = acc[mi][ni][r];
#pragma unroll
    for (int j = 0; j < 4; ++j) {
      int lr = j * 4 + rrow;
      float4v z = *(const float4v*)&Ts[lr * 68 + colg];
      size_t gm = (size_t)(tile_m + wave_m + mi * 16 + lr);
      short4v o;
      if (is_a) {
#pragma unroll
        for (int k = 0; k < 4; ++k) {
          float s = __builtin_amdgcn_rcpf(1.0f + __builtin_amdgcn_exp2f(-(z[k] + bias4[k]) * L2E));
          o[k] = f2h(s * la84[k]);
        }
        *(short4v*)(e_out + gm * D_DIM + ch0) = o;
      } else {
        short4v xq = *(const short4v*)(Xs + ((gm >> 4) * 32 * 64 + (gm & 15)) * 8 + xs_ch);
#pragma unroll
        for (int k = 0; k < 4; ++k) {
          float s = __builtin_amdgcn_rcpf(1.0f + __builtin_amdgcn_exp2f(-(z[k] + bias4[k]) * L2E));
          o[k] = (short)f2bf(s * bf2f((unsigned short)xq[k]));
        }
        *(short4v*)((short*)g_out + gm * D_DIM + ch0) = o;
      }
    }
  }
}

// Phase 1: per-chunk (P = prod a, Q = local scan from 0). a = exp2(e).
// grid (4, NC=64, 4) = 1024 blocks -> 4 blocks/CU.
__global__ void scan_phase1(const short* __restrict__ e, const unsigned short* __restrict__ g,
                            float* __restrict__ P, float* __restrict__ Q) {
  int d = blockIdx.x * 256 + threadIdx.x;
  int c = blockIdx.y;
  int b = blockIdx.z;
  const size_t base = ((size_t)(b * L_DIM + c * CL)) * D_DIM + d;
  float Pv = 1.0f, Qv = 0.0f;
#pragma unroll 4
  for (int t = 0; t < CL; ++t) {
    float ev = (float)__builtin_bit_cast(_Float16, e[base + (size_t)t * D_DIM]);
    float at = __builtin_amdgcn_exp2f(ev);
    float gv = bf2f(g[base + (size_t)t * D_DIM]);
    float bt = sqrtf(fmaxf(1.0f - at * at, 0.0f)) * gv;
    Qv = fmaf(at, Qv, bt);
    Pv *= at;
  }
  int idx = (b * NC + c) * D_DIM + d;
  P[idx] = Pv;
  Q[idx] = Qv;
}

// Phase 3: per-block prefix over earlier chunks (P,Q L2-resident), replay
// chunk, write y.
__global__ void scan_phase3(const short* __restrict__ e, const unsigned short* __restrict__ g,
                            const float* __restrict__ P, const float* __restrict__ Q,
                            float* __restrict__ y) {
  int d = blockIdx.x * 256 + threadIdx.x;
  int c = blockIdx.y;
  int b = blockIdx.z;
  float h = 0.0f;
#pragma unroll 4
  for (int cc = 0; cc < c; ++cc) {
    int idx = (b * NC + cc) * D_DIM + d;
    h = fmaf(P[idx], h, Q[idx]);
  }
  const size_t base = ((size_t)(b * L_DIM + c * CL)) * D_DIM + d;
#pragma unroll 4
  for (int t = 0; t < CL; ++t) {
    float ev = (float)__builtin_bit_cast(_Float16, e[base + (size_t)t * D_DIM]);
    float at = __builtin_amdgcn_exp2f(ev);
    float gv = bf2f(g[base + (size_t)t * D_DIM]);
    float bt = sqrtf(fmaxf(1.0f - at * at, 0.0f)) * gv;
    h = fmaf(at, h, bt);
    y[base + (size_t)t * D_DIM] = h;
  }
}

extern "C" void kernel_launch(void* const* d_in, const int* in_sizes, int n_in,
                              void* d_out, int out_size, void* d_ws, size_t ws_size,
                              hipStream_t stream) {
  const float* x    = (const float*)d_in[0];
  const float* Wa   = (const float*)d_in[1];
  const float* Wx   = (const float*)d_in[2];
  const float* ba   = (const float*)d_in[3];
  const float* bx   = (const float*)d_in[4];
  const float* lmbd = (const float*)d_in[5];
  float* y = (float*)d_out;

  char* ws = (char*)d_ws;
  short* Xs             = (short*)ws;                       // 32 MiB swizzled bf16 x
  short* Wsz            = (short*)(ws + 33554432);          //  4 MiB swizzled bf16 [Wa;Wx]
  short* e_buf          = (short*)(ws + 37748736);          // 32 MiB fp16 e
  unsigned short* g_buf = (unsigned short*)(ws + 71303168); // 32 MiB bf16 g
  float* P              = (float*)(ws + 104857600);         //  1 MiB
  float* Q              = (float*)(ws + 105906176);         //  1 MiB

  pack_all<<<(NX16 + NW16) / 256, 256, 0, stream>>>(x, Wa, Wx, Xs, Wsz);

  dim3 gg(N_DIM / 128, M_DIM / 128);   // (16, 128), n fastest
  gemm_gates<<<gg, 256, 0, stream>>>(Xs, Wsz, ba, bx, lmbd, e_buf, g_buf);

  dim3 sg(D_DIM / 256, NC, B_DIM);     // (4, 64, 4) = 1024 blocks
  scan_phase1<<<sg, 256, 0, stream>>>(e_buf, g_buf, P, Q);
  scan_phase3<<<sg, 256, 0, stream>>>(e_buf, g_buf, P, Q, y);
}